// Round 1
// baseline (163.726 us; speedup 1.0000x reference)
//
#include <hip/hip_runtime.h>
#include <hip/hip_bf16.h>

// Problem constants: p1,p2 : (B=2, C=32, D=H=W=64) fp32. Pool 4x4x4 -> S=16.
// N = B*S^3 = 8192 rows of C=32. loss = ||A Aᵀ - B Bᵀ||_F² / N²
//           = (||AᵀA||² - 2||AᵀB||² + ||BᵀB||²) / N²  with 32x32 Grams only.

#define HW   4096      // 64*64
#define DHW  262144    // 64*64*64
#define NROW 8192
#define C    32

// ---------------------------------------------------------------------------
// Kernel 1: fused 4x4x4 avg-pool + row L2-normalize.
// grid.x = 512 : (b,z,y) triples; grid.y = 2 : which input (p1 or p2).
// 256 threads: tid = c0*16 + x ; each thread produces pooled values for
// channels {c0, c0+16} at x-position x. Loads are float4 along W, 16 lanes
// contiguous (256B segments) -> coalesced.
// ---------------------------------------------------------------------------
__global__ __launch_bounds__(256) void pool_norm_kernel(
    const float* __restrict__ p1, const float* __restrict__ p2,
    float* __restrict__ An, float* __restrict__ Bn)
{
    const int bid = blockIdx.x;
    const int y = bid & 15;
    const int z = (bid >> 4) & 15;
    const int b = bid >> 8;

    const float* __restrict__ src = (blockIdx.y == 0) ? p1 : p2;
    float* __restrict__ dst       = (blockIdx.y == 0) ? An : Bn;

    const int tid = threadIdx.x;
    const int x  = tid & 15;
    const int c0 = tid >> 4;   // 0..15

    __shared__ float pool[C][16];   // [channel][x]
    __shared__ float inv_norm[16];

    float pooled[2];
    #pragma unroll
    for (int cc = 0; cc < 2; ++cc) {
        const int c = c0 + cc * 16;
        const float* base = src + (size_t)(b * C + c) * DHW
                                + (4 * z) * HW + (4 * y) * 64 + 4 * x;
        float s = 0.f;
        #pragma unroll
        for (int dz = 0; dz < 4; ++dz) {
            #pragma unroll
            for (int dy = 0; dy < 4; ++dy) {
                const float4 v = *reinterpret_cast<const float4*>(base + dz * HW + dy * 64);
                s += (v.x + v.y) + (v.z + v.w);
            }
        }
        pooled[cc] = s * (1.0f / 64.0f);
        pool[c][x] = pooled[cc];
    }
    __syncthreads();

    if (tid < 16) {
        float ss = 0.f;
        #pragma unroll
        for (int c = 0; c < C; ++c) { const float v = pool[c][tid]; ss += v * v; }
        inv_norm[tid] = 1.0f / fmaxf(sqrtf(ss), 1e-8f);
    }
    __syncthreads();

    const int row = ((b * 16 + z) * 16 + y) * 16 + x;   // b*4096 + z*256 + y*16 + x
    const float inv = inv_norm[x];
    #pragma unroll
    for (int cc = 0; cc < 2; ++cc) {
        const int c = c0 + cc * 16;
        dst[(size_t)row * C + c] = pooled[cc] * inv;
    }
}

// ---------------------------------------------------------------------------
// Kernel 2: three 32x32 Grams: Gaa = AᵀA, Gab = AᵀB, Gbb = BᵀB.
// 128 blocks x 256 threads, 64 rows/block (2 LDS tiles of 32 rows).
// Thread t owns entries (k = t>>3, l = (t&7)*4 .. +3) of all three Grams
// (12 accumulators in registers), then atomicAdds partials to global G.
// ---------------------------------------------------------------------------
__global__ __launch_bounds__(256) void gram_kernel(
    const float* __restrict__ An, const float* __restrict__ Bn,
    float* __restrict__ G)   // G[0..1023]=Gaa, [1024..2047]=Gab, [2048..3071]=Gbb
{
    const int tid = threadIdx.x;
    const int k  = tid >> 3;          // 0..31
    const int l4 = (tid & 7) * 4;     // 0,4,...,28

    __shared__ float As[32 * C];
    __shared__ float Bs[32 * C];

    float gaa[4] = {0.f, 0.f, 0.f, 0.f};
    float gab[4] = {0.f, 0.f, 0.f, 0.f};
    float gbb[4] = {0.f, 0.f, 0.f, 0.f};

    const int row0 = blockIdx.x * 64;
    for (int t = 0; t < 2; ++t) {
        const int r = row0 + t * 32;
        // stage 32 rows x 32 cols = 1024 floats = 256 float4 per matrix
        reinterpret_cast<float4*>(As)[tid] =
            reinterpret_cast<const float4*>(An + (size_t)r * C)[tid];
        reinterpret_cast<float4*>(Bs)[tid] =
            reinterpret_cast<const float4*>(Bn + (size_t)r * C)[tid];
        __syncthreads();

        #pragma unroll
        for (int i = 0; i < 32; ++i) {
            const float a_k = As[i * C + k];
            const float b_k = Bs[i * C + k];
            const float4 a_l = *reinterpret_cast<const float4*>(&As[i * C + l4]);
            const float4 b_l = *reinterpret_cast<const float4*>(&Bs[i * C + l4]);
            gaa[0] += a_k * a_l.x;  gaa[1] += a_k * a_l.y;
            gaa[2] += a_k * a_l.z;  gaa[3] += a_k * a_l.w;
            gab[0] += a_k * b_l.x;  gab[1] += a_k * b_l.y;
            gab[2] += a_k * b_l.z;  gab[3] += a_k * b_l.w;
            gbb[0] += b_k * b_l.x;  gbb[1] += b_k * b_l.y;
            gbb[2] += b_k * b_l.z;  gbb[3] += b_k * b_l.w;
        }
        __syncthreads();
    }

    float* Gaa = G;
    float* Gab = G + 1024;
    float* Gbb = G + 2048;
    #pragma unroll
    for (int j = 0; j < 4; ++j) {
        atomicAdd(&Gaa[k * C + l4 + j], gaa[j]);
        atomicAdd(&Gab[k * C + l4 + j], gab[j]);
        atomicAdd(&Gbb[k * C + l4 + j], gbb[j]);
    }
}

// ---------------------------------------------------------------------------
// Kernel 3: loss = (sum Gaa² - 2 sum Gab² + sum Gbb²) / N²
// ---------------------------------------------------------------------------
__global__ __launch_bounds__(1024) void finalize_kernel(
    const float* __restrict__ G, float* __restrict__ out)
{
    const int t = threadIdx.x;
    const float gaa = G[t];
    const float gab = G[1024 + t];
    const float gbb = G[2048 + t];
    float v = gaa * gaa + gbb * gbb - 2.f * gab * gab;

    __shared__ float red[16];
    #pragma unroll
    for (int off = 32; off > 0; off >>= 1) v += __shfl_down(v, off);
    if ((t & 63) == 0) red[t >> 6] = v;
    __syncthreads();
    if (t < 16) {
        float w = red[t];
        #pragma unroll
        for (int off = 8; off > 0; off >>= 1) w += __shfl_down(w, off);
        if (t == 0) out[0] = w / ((float)NROW * (float)NROW);
    }
}

extern "C" void kernel_launch(void* const* d_in, const int* in_sizes, int n_in,
                              void* d_out, int out_size, void* d_ws, size_t ws_size,
                              hipStream_t stream) {
    const float* p1 = (const float*)d_in[0];
    const float* p2 = (const float*)d_in[1];
    float* out = (float*)d_out;

    float* An = (float*)d_ws;                    // 8192*32 floats = 1 MiB
    float* Bn = An + (size_t)NROW * C;           // 1 MiB
    float* G  = Bn + (size_t)NROW * C;           // 3*1024 floats = 12 KiB

    hipMemsetAsync(G, 0, 3 * 1024 * sizeof(float), stream);

    dim3 g1(512, 2);
    pool_norm_kernel<<<g1, 256, 0, stream>>>(p1, p2, An, Bn);
    gram_kernel<<<128, 256, 0, stream>>>(An, Bn, G);
    finalize_kernel<<<1, 1024, 0, stream>>>(G, out);
}